// Round 9
// baseline (427.068 us; speedup 1.0000x reference)
//
#include <hip/hip_runtime.h>
#include <hip/hip_bf16.h>

// RelationAwareSelfAttention  N=500, DM=DK=DV=2048, KWIN=10
// Round 9: single persistent 256-block kernel, manual device-scope grid
// barrier between phases (grid==256<=CUs, 1 block/CU guaranteed, counter
// memset to 0 on stream each call). Dbuf LDS gemm core (1 barrier/iter).
// Vt computed as bf16 transpose of V (Vt gemm deleted). Wo^T overlapped
// with QKV gemm. 1 launch + 1 memset.

#define N_TOK 500
#define MP 512
#define DM 2048
#define KWIN_ 10
#define NREL 21
#define NB 256

typedef __hip_bfloat16 bf16;
typedef __attribute__((ext_vector_type(8))) short short8;
typedef __attribute__((ext_vector_type(4))) float floatx4;

#define NS 262144L  // 512*512

__device__ inline float bfj(const short8& v, int j) {
  return __bfloat162float(((const bf16*)&v)[j]);
}

// ---- device-scope grid barrier (monotonic counter; it = 1,2,3,...) ----
__device__ __forceinline__ void gsync(int* bar, int it) {
  __syncthreads();
  if (threadIdx.x == 0) {
    __threadfence();  // release my block's writes
    atomicAdd(bar, 1);
    while (__hip_atomic_load(bar, __ATOMIC_ACQUIRE,
                             __HIP_MEMORY_SCOPE_AGENT) < NB * it)
      __builtin_amdgcn_s_sleep(1);
  }
  __syncthreads();
  __threadfence();  // acquire: invalidate L1 before reading others' data
}

// ---- 64x64 f32->bf16 transposing tile (XOR-swizzled, R8-proven) ----
__device__ __forceinline__ void transpose_tile(const float* __restrict__ W,
                                               bf16* __restrict__ Out, int k0,
                                               int n0, char* sm) {
  float (*t)[68] = (float(*)[68])sm;
  int tid = threadIdx.x;
  int rr = tid >> 4, cc = (tid & 15) * 4;
  int gsw = cc >> 2;
#pragma unroll
  for (int p = 0; p < 4; ++p) {
    int r = rr + 16 * p;
    float4 v = *(const float4*)(W + (long)(k0 + r) * DM + n0 + cc);
    *(float4*)&t[r][(gsw ^ (r & 3)) * 4] = v;
  }
  __syncthreads();
#pragma unroll
  for (int s0 = 0; s0 < 2; ++s0) {
    int s = tid + s0 * 256;
    int n = s >> 3, c = s & 7;
    bf16 v[8];
#pragma unroll
    for (int j = 0; j < 8; ++j) {
      int rowt = c * 8 + j;
      int col = ((n >> 2) ^ (rowt & 3)) * 4 + (n & 3);
      v[j] = __float2bfloat16(t[rowt][col]);
    }
    *(short8*)(Out + (long)(n0 + n) * DM + k0 + c * 8) = *(short8*)v;
  }
  __syncthreads();
}

// ---- 64x64 bf16 tile transpose: dst[c][r] = src[r][c] ----
__device__ __forceinline__ void transpose_bf(const bf16* __restrict__ src,
                                             int lds, bf16* __restrict__ dst,
                                             int ldd, int r0, int c0,
                                             char* sm) {
  unsigned short (*t)[72] = (unsigned short(*)[72])sm;
  const unsigned short* s = (const unsigned short*)src;
  unsigned short* d = (unsigned short*)dst;
  int tid = threadIdx.x;
  int c = tid & 63, r4 = tid >> 6;
#pragma unroll
  for (int i = 0; i < 16; ++i) {
    int r = r4 * 16 + i;
    t[r][c] = s[(long)(r0 + r) * lds + c0 + c];
  }
  __syncthreads();
#pragma unroll
  for (int i = 0; i < 16; ++i) {
    int r = r4 * 16 + i;
    d[(long)(c0 + r) * ldd + r0 + c] = t[c][r];
  }
  __syncthreads();
}

// ------- gemm core: 128x128 tile, 4 waves of 64x64, reg prefetch +
// double-buffered LDS (one barrier per K-iter). OUT: 0 f32, 1 bf16,
// 2 f32 atomicAdd rows < m_store. K multiple of 32, no edge guards. -------
template <int OUT>
__device__ __forceinline__ void gemm_core(
    const bf16* __restrict__ A, int lda, const bf16* __restrict__ B, int ldb,
    float* __restrict__ Cf, bf16* __restrict__ Cb, int ldc, int kStart,
    int kLen, int row0, int col0, int m_store, char* sm) {
  bf16* As = (bf16*)sm;            // [2][128][32]
  bf16* Bs = (bf16*)(sm + 16384);  // [2][128][32]
  int tid = threadIdx.x;
  int lane = tid & 63, w = tid >> 6;
  int wr = (w & 1) * 64, wc = (w >> 1) * 64;
  int l16 = lane & 15, l4 = lane >> 4;
  int r1 = tid >> 2, c1 = (tid & 3) * 8;
  int soff = r1 * 32 + c1;
  const bf16* a1p = A + (long)(row0 + r1) * lda + kStart + c1;
  const bf16* a2p = a1p + 64 * (long)lda;
  const bf16* b1p = B + (long)(col0 + r1) * ldb + kStart + c1;
  const bf16* b2p = b1p + 64 * (long)ldb;
  floatx4 acc[4][4] = {};
  short8 pa0 = *(const short8*)a1p, pa1 = *(const short8*)a2p;
  short8 pb0 = *(const short8*)b1p, pb1 = *(const short8*)b2p;
  // stage buf0
  *(short8*)(As + soff) = pa0;
  *(short8*)(As + 2048 + soff) = pa1;
  *(short8*)(Bs + soff) = pb0;
  *(short8*)(Bs + 2048 + soff) = pb1;
  if (kLen > 32) {  // prefetch iter 1
    pa0 = *(const short8*)(a1p + 32);
    pa1 = *(const short8*)(a2p + 32);
    pb0 = *(const short8*)(b1p + 32);
    pb1 = *(const short8*)(b2p + 32);
  }
  __syncthreads();
  int cur = 0;
  for (int k0 = 0; k0 < kLen; k0 += 32) {
    int cb = cur * 4096, nb = (cur ^ 1) * 4096;
    short8 af[4], bg[4];
#pragma unroll
    for (int g = 0; g < 4; ++g)
      af[g] = *(short8*)(As + cb + (wr + g * 16 + l16) * 32 + l4 * 8);
#pragma unroll
    for (int g = 0; g < 4; ++g)
      bg[g] = *(short8*)(Bs + cb + (wc + g * 16 + l16) * 32 + l4 * 8);
    if (k0 + 32 < kLen) {  // stage next buf (overlaps MFMA; no extra barrier)
      *(short8*)(As + nb + soff) = pa0;
      *(short8*)(As + nb + 2048 + soff) = pa1;
      *(short8*)(Bs + nb + soff) = pb0;
      *(short8*)(Bs + nb + 2048 + soff) = pb1;
      if (k0 + 64 < kLen) {
        pa0 = *(const short8*)(a1p + k0 + 64);
        pa1 = *(const short8*)(a2p + k0 + 64);
        pb0 = *(const short8*)(b1p + k0 + 64);
        pb1 = *(const short8*)(b2p + k0 + 64);
      }
    }
#pragma unroll
    for (int g = 0; g < 4; ++g)
#pragma unroll
      for (int h = 0; h < 4; ++h)
        acc[g][h] =
            __builtin_amdgcn_mfma_f32_16x16x32_bf16(af[g], bg[h], acc[g][h], 0, 0, 0);
    __syncthreads();
    cur ^= 1;
  }
  // C/D layout: col = lane&15, row = (lane>>4)*4 + i  [m89-verified]
#pragma unroll
  for (int g = 0; g < 4; ++g)
#pragma unroll
    for (int h = 0; h < 4; ++h)
#pragma unroll
      for (int i = 0; i < 4; ++i) {
        long r = row0 + wr + g * 16 + l4 * 4 + i;
        long c = col0 + wc + h * 16 + l16;
        if (OUT == 0)
          Cf[r * ldc + c] = acc[g][h][i];
        else if (OUT == 1)
          Cb[r * ldc + c] = __float2bfloat16(acc[g][h][i]);
        else if (r < m_store)
          atomicAdd(&Cf[r * ldc + c], acc[g][h][i]);
      }
}

// ---- softmax row: QR(21 dots) + sum 8 S-partials + bias + mask + softmax ----
__device__ __forceinline__ void softmax_row(
    int i, const float* __restrict__ Sp, const bf16* __restrict__ QKVbf,
    const bf16* __restrict__ wkb, const int* __restrict__ mask,
    float* __restrict__ Aout, bf16* __restrict__ Abf, char* sm) {
  int tid = threadIdx.x;
  if (i >= N_TOK) {  // pad rows of Abf -> 0
    Abf[(long)i * MP + tid] = __float2bfloat16(0.f);
    Abf[(long)i * MP + tid + 256] = __float2bfloat16(0.f);
    return;
  }
  float* sQR = (float*)sm;
  float* red = (float*)sm + 24;
  int lane = tid & 63, w = tid >> 6;
  short8 q[4];
#pragma unroll
  for (int s = 0; s < 4; ++s)
    q[s] = *(const short8*)(QKVbf + (long)i * 6144 + s * 512 + lane * 8);
  for (int r = w; r < NREL; r += 4) {
    float p = 0.f;
#pragma unroll
    for (int s = 0; s < 4; ++s) {
      short8 wv = *(const short8*)(wkb + (long)r * DM + s * 512 + lane * 8);
#pragma unroll
      for (int j = 0; j < 8; ++j) p += bfj(q[s], j) * bfj(wv, j);
    }
#pragma unroll
    for (int o = 32; o > 0; o >>= 1) p += __shfl_down(p, o);
    if (lane == 0) sQR[r] = p;
  }
  __syncthreads();
  const float scale = 0.022097086912079608f;  // 1/sqrt(2048)
  float v0, v1 = -1e30f;
  int j0 = tid, j1 = tid + 256;
  {
    float s = 0.f;
#pragma unroll
    for (int z = 0; z < 8; ++z) s += Sp[z * NS + (long)i * MP + j0];
    int rel = j0 - i;
    rel = rel < -KWIN_ ? -KWIN_ : (rel > KWIN_ ? KWIN_ : rel);
    s = scale * (s + sQR[rel + KWIN_]);
    if (mask[(long)i * N_TOK + j0] == 0) s = -1e9f;
    v0 = s;
  }
  if (j1 < N_TOK) {
    float s = 0.f;
#pragma unroll
    for (int z = 0; z < 8; ++z) s += Sp[z * NS + (long)i * MP + j1];
    int rel = j1 - i;
    rel = rel < -KWIN_ ? -KWIN_ : (rel > KWIN_ ? KWIN_ : rel);
    s = scale * (s + sQR[rel + KWIN_]);
    if (mask[(long)i * N_TOK + j1] == 0) s = -1e9f;
    v1 = s;
  }
  float mx = fmaxf(v0, v1);
#pragma unroll
  for (int o = 32; o > 0; o >>= 1) mx = fmaxf(mx, __shfl_down(mx, o));
  if (lane == 0) red[w] = mx;
  __syncthreads();
  if (tid == 0) red[0] = fmaxf(fmaxf(red[0], red[1]), fmaxf(red[2], red[3]));
  __syncthreads();
  mx = red[0];
  __syncthreads();
  float e0 = expf(v0 - mx);
  float e1 = (j1 < N_TOK) ? expf(v1 - mx) : 0.f;
  float sum = e0 + e1;
#pragma unroll
  for (int o = 32; o > 0; o >>= 1) sum += __shfl_down(sum, o);
  if (lane == 0) red[w] = sum;
  __syncthreads();
  if (tid == 0) red[0] = red[0] + red[1] + red[2] + red[3];
  __syncthreads();
  float inv = 1.f / red[0];
  float a0 = e0 * inv, a1 = e1 * inv;
  Aout[(long)i * N_TOK + j0] = a0;
  if (j1 < N_TOK) Aout[(long)i * N_TOK + j1] = a1;
  Abf[(long)i * MP + j0] = __float2bfloat16(a0);
  Abf[(long)i * MP + j1] = __float2bfloat16(a1);  // j1>=500 -> 0
  __syncthreads();  // sQR/red reused by next row
}

// --------------------------- the persistent kernel ---------------------------
__global__ __launch_bounds__(256, 1) void fused(
    const float* __restrict__ X, const int* __restrict__ mask,
    const float* __restrict__ Wq, const float* __restrict__ Wk,
    const float* __restrict__ Wv, const float* __restrict__ Wo,
    const float* __restrict__ wk, float* __restrict__ Yout,
    float* __restrict__ Aout, char* __restrict__ ws, int* __restrict__ bar) {
  __shared__ __align__(16) char sm[32768];
  const long MB = 1 << 20;
  bf16* Xb = (bf16*)ws;                  // [512][2048]
  bf16* WqkvT = (bf16*)(ws + 2 * MB);    // [6144][2048]
  bf16* WoT = (bf16*)(ws + 26 * MB);     // [2048][2048]
  bf16* wkb = (bf16*)(ws + 34 * MB);     // [21][2048]
  bf16* QKVbf = (bf16*)(ws + 35 * MB);   // [512][6144]
  bf16* Vtb = (bf16*)(ws + 41 * MB);     // [2048][512]
  float* Sp = (float*)(ws + 43 * MB);    // [8][512][512]
  bf16* Abf = (bf16*)(ws + 51 * MB);     // [512][512]
  bf16* AVbf = (bf16*)(ws + 52 * MB);    // [512][2048]
  int bid = blockIdx.x;
  int tid = threadIdx.x;

  // ---- phase 0: Wq/Wk/Wv transpose (3072), X/wk cvt (533), Y zero (500) ----
  for (int j = bid; j < 4105; j += NB) {
    if (j < 3072) {
      int z = j >> 10, t = j & 1023;
      const float* W = (z == 0) ? Wq : (z == 1) ? Wk : Wv;
      transpose_tile(W, WqkvT + (long)z * DM * DM, (t >> 5) * 64,
                     (t & 31) * 64, sm);
    } else if (j < 3605) {
      int r = j - 3072;
      bf16 v[8];
      if (r < MP) {
        if (r < N_TOK) {
          const float* p = X + (long)r * DM + tid * 8;
#pragma unroll
          for (int q = 0; q < 8; ++q) v[q] = __float2bfloat16(p[q]);
        } else {
#pragma unroll
          for (int q = 0; q < 8; ++q) v[q] = __float2bfloat16(0.f);
        }
        *(short8*)(Xb + (long)r * DM + tid * 8) = *(short8*)v;
      } else {
        int rr = r - MP;  // < 21
        const float* p = wk + (long)rr * DM + tid * 8;
#pragma unroll
        for (int q = 0; q < 8; ++q) v[q] = __float2bfloat16(p[q]);
        *(short8*)(wkb + (long)rr * DM + tid * 8) = *(short8*)v;
      }
    } else {
      int r = j - 3605;  // < 500: zero Y row for phase-5 atomics
      float4 z4 = {0.f, 0.f, 0.f, 0.f};
      float* yr = Yout + (long)r * DM + tid * 8;
      *(float4*)yr = z4;
      *(float4*)(yr + 4) = z4;
    }
  }
  gsync(bar, 1);

  // ---- phase 1: QKV gemm (192 blocks) || Wo transpose (64 blocks) ----
  if (bid < 192) {
    int row0 = (bid / 48) * 128, col0 = (bid % 48) * 128;
    gemm_core<1>(Xb, DM, WqkvT, DM, nullptr, QKVbf, 6144, 0, DM, row0, col0,
                 0, sm);
  } else {
    for (int t = bid - 192; t < 1024; t += 64)
      transpose_tile(Wo, WoT, (t >> 5) * 64, (t & 31) * 64, sm);
  }
  gsync(bar, 2);

  // ---- phase 2: S splitK8 (128 jobs) + Vt bf16 transpose (256 jobs) ----
  for (int j = bid; j < 384; j += NB) {
    if (j < 128) {
      int z = j >> 4, t = j & 15;
      gemm_core<0>(QKVbf, 6144, QKVbf + 2048, 6144, Sp + (long)z * NS, nullptr,
                   MP, z * 256, 256, (t >> 2) * 128, (t & 3) * 128, 0, sm);
    } else {
      int t = j - 128;  // V[512,2048] -> Vtb[2048,512]
      transpose_bf(QKVbf + 4096, 6144, Vtb, MP, (t >> 5) * 64, (t & 31) * 64,
                   sm);
    }
  }
  gsync(bar, 3);

  // ---- phase 3: softmax + QR (512 rows) ----
  for (int i = bid; i < MP; i += NB)
    softmax_row(i, Sp, QKVbf, wkb, mask, Aout, Abf, sm);
  gsync(bar, 4);

  // ---- phase 4: AV = Abf @ Vtb^T (64 jobs) ----
  if (bid < 64)
    gemm_core<1>(Abf, MP, Vtb, MP, nullptr, AVbf, DM, 0, MP, (bid >> 4) * 128,
                 (bid & 15) * 128, 0, sm);
  gsync(bar, 5);

  // ---- phase 5: Y = AV @ WoT^T splitK2, atomicAdd rows < 500 ----
  if (bid < 128) {
    int z = bid >> 6, t = bid & 63;
    gemm_core<2>(AVbf, DM, WoT, DM, Yout, nullptr, DM, z * 1024, 1024,
                 (t >> 4) * 128, (t & 15) * 128, N_TOK, sm);
  }
}

extern "C" void kernel_launch(void* const* d_in, const int* in_sizes, int n_in,
                              void* d_out, int out_size, void* d_ws,
                              size_t ws_size, hipStream_t stream) {
  const float* X = (const float*)d_in[0];
  const int* mask = (const int*)d_in[1];
  const float* Wq = (const float*)d_in[2];
  const float* Wk = (const float*)d_in[3];
  const float* Wv = (const float*)d_in[4];
  const float* Wo = (const float*)d_in[5];
  const float* wk = (const float*)d_in[6];

  float* Yout = (float*)d_out;            // [500,2048]
  float* Aout = Yout + (long)N_TOK * DM;  // [500,500]

  char* ws = (char*)d_ws;
  int* bar = (int*)(ws + 56 * (1L << 20));

  hipMemsetAsync(bar, 0, 256, stream);  // zero grid-barrier counter
  fused<<<dim3(NB), dim3(256), 0, stream>>>(X, mask, Wq, Wk, Wv, Wo, wk, Yout,
                                            Aout, ws, bar);
}